// Round 3
// baseline (1092.321 us; speedup 1.0000x reference)
//
#include <hip/hip_runtime.h>
#include <hip/hip_cooperative_groups.h>
namespace cg = cooperative_groups;

typedef unsigned short u16;
typedef short v8s __attribute__((ext_vector_type(8)));
typedef float v4f __attribute__((ext_vector_type(4)));
typedef u16  v4u __attribute__((ext_vector_type(4)));

__device__ __forceinline__ float bf2f(u16 h){ return __uint_as_float(((unsigned)h)<<16); }
__device__ __forceinline__ u16 f2bf(float f){
  unsigned u = __float_as_uint(f);
  u += 0x7FFFu + ((u>>16)&1u);
  return (u16)(u>>16);
}
__device__ __forceinline__ float siluf(float x){ return x/(1.f+__expf(-x)); }
__device__ __forceinline__ float softplusf(float x){
  return (x>15.f) ? x : __logf(1.f+__expf(x));
}

// ===========================================================================
// PRIMARY PATH: one persistent cooperative kernel, grid.sync() between stages.
// Weights are converted f32->bf16 on the fly in the GEMM B-staging path.
// ===========================================================================
struct Params {
  const float *x,*w_in,*b_in,*ln_g,*ln_b,*W_inproj,*conv_w,*conv_b,*W_xproj,
              *W_dt,*b_dt,*D_skip,*W_outproj,*w_log,*b_log,*W_gate,*b_gate,
              *W_h1,*b_h1,*W_h2,*b_h2;
  float* out;
  float* h;   // 1024x512 f32 residual
  u16*   hn;  // 1024x512 bf16
  u16*   u;   // 1024x1536 bf16
  u16*   zs;  // 1024x1536 bf16
  u16*   dtb; // 1024x32 bf16
  float* sb;  // 1024 f32
  u16*   y;   // 1024x1536 bf16
};

// A bf16 row-major (lda), B f32 row-major (ldb) converted to bf16 during
// LDS staging. Register-prefetch pipelined K-loop (32 per iter).
// MODE 0: G1 epilogue -> u=silu(conv_tap)+ / zs=silu(z)
// MODE 1: G2: acc -> LDS tile, then s[b]=dot(Bm,Cm), dt->bf16 (in-block sdt)
// MODE 2: G3 epilogue -> y = u*(softplus(acc+bdt)*s + Dp)*zs
// MODE 3: G4 epilogue -> atomicAdd into f32 h
template<int BM,int BN,int WM,int WN,int MODE>
__device__ __forceinline__ void gemm_tile(
  const u16* __restrict__ A, int lda,
  const float* __restrict__ Bw, int ldb,
  int m0, int n0, int k0, int Klen,
  u16* As, u16* Bs, float* Ot,
  const float* __restrict__ p0, const float* __restrict__ p1,
  const float* __restrict__ p2,
  const u16* __restrict__ q0, const u16* __restrict__ q1,
  u16* __restrict__ o16a, u16* __restrict__ o16b, float* __restrict__ o32,
  u16* __restrict__ dtb, float* __restrict__ sb)
{
  constexpr int MI=WM/16, NI=WN/16, WCOLS=BN/WN;
  constexpr int LDSK=40;            // 32+8 pad
  constexpr int CA=BM*4;            // 8-elem bf16 chunks of A
  constexpr int CB=BN*8;            // 4-elem f32 chunks of B
  constexpr int IA=(CA+255)/256, IB=(CB+255)/256;
  const int tid=threadIdx.x, lane=tid&63, wid=tid>>6;
  const int wm=wid/WCOLS, wn=wid%WCOLS;
  const int qd=lane>>4, lr=lane&15;

  v4f acc[MI][NI];
#pragma unroll
  for(int i=0;i<MI;i++)
#pragma unroll
    for(int j=0;j<NI;j++) acc[i][j]=v4f{0.f,0.f,0.f,0.f};

  v8s ra[IA]; float4 rb[IB];
  auto loadAB=[&](int kk){
#pragma unroll
    for(int i=0;i<IA;i++){ int s=tid+i*256;
      if(CA%256==0 || s<CA){ int r=s>>2,kg=s&3;
        ra[i]=*(const v8s*)(A+(size_t)(m0+r)*lda+(k0+kk)+kg*8); } }
#pragma unroll
    for(int i=0;i<IB;i++){ int s=tid+i*256;
      if(CB%256==0 || s<CB){ int r=s>>3,kg=s&7;
        rb[i]=*(const float4*)(Bw+(size_t)(n0+r)*ldb+(k0+kk)+kg*4); } }
  };

  loadAB(0);
  for(int kk=0;kk<Klen;kk+=32){
    __syncthreads();
#pragma unroll
    for(int i=0;i<IA;i++){ int s=tid+i*256;
      if(CA%256==0 || s<CA){ int r=s>>2,kg=s&3;
        *(v8s*)(As+r*LDSK+kg*8)=ra[i]; } }
#pragma unroll
    for(int i=0;i<IB;i++){ int s=tid+i*256;
      if(CB%256==0 || s<CB){ int r=s>>3,kg=s&7;
        v4u pk={ f2bf(rb[i].x), f2bf(rb[i].y), f2bf(rb[i].z), f2bf(rb[i].w) };
        *(v4u*)(Bs+r*LDSK+kg*4)=pk; } }
    __syncthreads();
    if(kk+32<Klen) loadAB(kk+32);   // in flight during MFMA
    v8s af[MI], bfv[NI];
#pragma unroll
    for(int i=0;i<MI;i++) af[i]=*(const v8s*)(As+(wm*WM+i*16+lr)*LDSK+qd*8);
#pragma unroll
    for(int j=0;j<NI;j++) bfv[j]=*(const v8s*)(Bs+(wn*WN+j*16+lr)*LDSK+qd*8);
#pragma unroll
    for(int i=0;i<MI;i++)
#pragma unroll
      for(int j=0;j<NI;j++)
        acc[i][j]=__builtin_amdgcn_mfma_f32_16x16x32_bf16(af[i],bfv[j],acc[i][j],0,0,0);
  }

  if constexpr(MODE==1){
    // stash score tile, then in-block sdt
#pragma unroll
    for(int i=0;i<MI;i++)
#pragma unroll
      for(int j=0;j<NI;j++){
        int lr0=wm*WM+i*16+qd*4, lc=wn*WN+j*16+lr;
#pragma unroll
        for(int r=0;r<4;r++) Ot[(lr0+r)*97+lc]=acc[i][j][r];
      }
    __syncthreads();
    int r4=tid>>2, sub=tid&3;
    const float* orow = Ot + r4*97;
    float s_=0.f;
#pragma unroll
    for(int i=0;i<8;i++){ int n=sub*8+i; s_ += orow[32+n]*orow[64+n]; }
    s_ += __shfl_xor(s_,1); s_ += __shfl_xor(s_,2);
    if(sub==0) sb[m0+r4]=s_;
#pragma unroll
    for(int i=0;i<8;i++){ int c=sub*8+i; dtb[(size_t)(m0+r4)*32+c]=f2bf(orow[c]); }
  } else {
#pragma unroll
    for(int i=0;i<MI;i++)
#pragma unroll
      for(int j=0;j<NI;j++){
        const int gb0=m0+wm*WM+i*16+qd*4;
        const int ge =n0+wn*WN+j*16+lr;
#pragma unroll
        for(int r=0;r<4;r++){
          const int gb=gb0+r;
          float val=acc[i][j][r];
          if constexpr(MODE==0){
            if(ge<1536){
              float t=val*p0[ge*4+3]+p1[ge];
              o16a[(size_t)gb*1536+ge]=f2bf(siluf(t));
            }else{
              o16b[(size_t)gb*1536+(ge-1536)]=f2bf(siluf(val));
            }
          } else if constexpr(MODE==2){
            float delta=softplusf(val+p0[ge]);
            float uu=bf2f(q0[(size_t)gb*1536+ge]);
            float zz=bf2f(q1[(size_t)gb*1536+ge]);
            o16a[(size_t)gb*1536+ge]=f2bf(uu*(delta*p2[gb]+p1[ge])*zz);
          } else {
            atomicAdd(o32+(size_t)gb*512+ge, val);
          }
        }
      }
  }
}

__global__ __launch_bounds__(256,2) void mega_kernel(Params p)
{
  cg::grid_group grid = cg::this_grid();
  __shared__ u16 As[64*40];
  __shared__ u16 Bs[96*40];
  __shared__ float Ot[64*97];
  __shared__ float red[8];
  __shared__ float fused[512];
  __shared__ float part[256];
  __shared__ float z1s[32];
  const int bid=blockIdx.x, nb=gridDim.x, tid=threadIdx.x;

  // ---- S0: input MLP -> h ----
  for(int idx=bid*256+tid; idx<1024*512; idx+=nb*256){
    int b=idx>>9, d=idx&511;
    const float* xr=p.x+b*68+4;
    const float* wr=p.w_in+d*64;
    float a=p.b_in[d];
#pragma unroll
    for(int f=0;f<64;f++) a+=xr[f]*wr[f];
    p.h[idx]=fmaxf(a,0.f);
  }
  grid.sync();

  for(int l=0;l<4;l++){
    // ---- S1: LayerNorm -> hn (bf16) ----
    const float* g=p.ln_g+l*512; const float* bt=p.ln_b+l*512;
    for(int row=bid; row<1024; row+=nb){
      __syncthreads();
      float v0=p.h[row*512+tid], v1=p.h[row*512+256+tid];
      float s=v0+v1, s2=v0*v0+v1*v1;
#pragma unroll
      for(int off=32; off; off>>=1){ s+=__shfl_down(s,off); s2+=__shfl_down(s2,off); }
      if((tid&63)==0){ red[(tid>>6)*2]=s; red[(tid>>6)*2+1]=s2; }
      __syncthreads();
      float mu=(red[0]+red[2]+red[4]+red[6])*(1.f/512.f);
      float ms=(red[1]+red[3]+red[5]+red[7])*(1.f/512.f);
      float rstd=rsqrtf(ms-mu*mu+1e-5f);
      p.hn[row*512+tid]    =f2bf((v0-mu)*rstd*g[tid]    +bt[tid]);
      p.hn[row*512+256+tid]=f2bf((v1-mu)*rstd*g[tid+256]+bt[tid+256]);
    }
    grid.sync();
    // ---- S2: G1 hn @ W_inproj^T -> u|zs (768 tiles) ----
    for(int t=bid; t<768; t+=nb){
      int mt=t/48, nt=t%48;
      gemm_tile<64,64,32,32,0>(p.hn,512, p.W_inproj+(size_t)l*3072*512,512,
        mt*64, nt*64, 0, 512, As,Bs,Ot,
        p.conv_w+l*6144, p.conv_b+l*1536, nullptr, nullptr,nullptr,
        p.u, p.zs, nullptr, nullptr,nullptr);
    }
    grid.sync();
    // ---- S3: G2 u @ W_xproj^T (N=96 per block) + in-block sdt (16 tiles) ----
    for(int t=bid; t<16; t+=nb){
      gemm_tile<64,96,32,48,1>(p.u,1536, p.W_xproj+(size_t)l*96*1536,1536,
        t*64, 0, 0, 1536, As,Bs,Ot,
        nullptr,nullptr,nullptr,nullptr,nullptr,
        nullptr,nullptr,nullptr, p.dtb, p.sb);
    }
    grid.sync();
    // ---- S4: G3 dtb @ W_dt^T -> y (384 tiles, K=32) ----
    for(int t=bid; t<384; t+=nb){
      int mt=t/24, nt=t%24;
      gemm_tile<64,64,32,32,2>(p.dtb,32, p.W_dt+(size_t)l*1536*32,32,
        mt*64, nt*64, 0, 32, As,Bs,Ot,
        p.b_dt+l*1536, p.D_skip+l*1536, p.sb, p.u, p.zs,
        p.y, nullptr, nullptr, nullptr,nullptr);
    }
    grid.sync();
    // ---- S5: G4 y @ W_outproj^T, split-K=4, atomicAdd into h (512 tiles) ----
    for(int t=bid; t<512; t+=nb){
      int z=t&3, nt=(t>>2)&7, mt=t>>5;
      gemm_tile<64,64,32,32,3>(p.y,1536, p.W_outproj+(size_t)l*512*1536,1536,
        mt*64, nt*64, z*384, 384, As,Bs,Ot,
        nullptr,nullptr,nullptr,nullptr,nullptr,
        nullptr,nullptr, p.h, nullptr,nullptr);
    }
    grid.sync();
  }

  // ---- S6: head ----
  for(int b=bid; b<1024; b+=nb){
    __syncthreads();
    float lgin=p.x[b*68+0]*p.w_log[0]+p.x[b*68+1]*p.w_log[1]
              +p.x[b*68+2]*p.w_log[2]+p.x[b*68+3]*p.w_log[3]+p.b_log[0];
    float lg=1.f/(1.f+__expf(-lgin));
    for(int d=tid; d<512; d+=256)
      fused[d]=p.h[(size_t)b*512+d]*(lg*p.W_gate[d]+p.b_gate[d]);
    __syncthreads();
    int j=tid&31, c=tid>>5;
    float pp=0.f;
#pragma unroll
    for(int i=0;i<64;i++){ int d=c*64+i; pp+=fused[d]*p.W_h1[j*512+d]; }
    part[tid]=pp;
    __syncthreads();
    if(tid<32){
      float z=p.b_h1[tid];
#pragma unroll
      for(int cc=0;cc<8;cc++) z+=part[cc*32+tid];
      z1s[tid]=fmaxf(z,0.f);
    }
    __syncthreads();
    if(tid==0){
      float lo=p.b_h2[0];
#pragma unroll
      for(int jj=0;jj<32;jj++) lo+=z1s[jj]*p.W_h2[jj];
      p.out[b]=1.f/(1.f+__expf(-lo));
    }
  }
}

// ===========================================================================
// FALLBACK PATH (R2 kernels, verbatim) — used only if cooperative launch fails
// ===========================================================================
__global__ __launch_bounds__(256) void cvt_kernel(
  const float* __restrict__ s0, const float* __restrict__ s1,
  const float* __restrict__ s2, const float* __restrict__ s3,
  u16* __restrict__ d0, u16* __restrict__ d1,
  u16* __restrict__ d2, u16* __restrict__ d3)
{
  const int c0=6291456, c1=c0+589824, c2=c1+196608, c3=c2+3145728;
  int i4 = (blockIdx.x*256 + threadIdx.x)*4;
  if(i4 >= c3) return;
  const float* src; u16* dst; int off;
  if(i4 < c0){ src=s0; dst=d0; off=i4; }
  else if(i4 < c1){ src=s1; dst=d1; off=i4-c0; }
  else if(i4 < c2){ src=s2; dst=d2; off=i4-c1; }
  else           { src=s3; dst=d3; off=i4-c2; }
  float4 v = *(const float4*)(src+off);
  v4u o = { f2bf(v.x), f2bf(v.y), f2bf(v.z), f2bf(v.w) };
  *(v4u*)(dst+off) = o;
}

__global__ __launch_bounds__(256) void input_kernel(
  const float* __restrict__ x, const float* __restrict__ w,
  const float* __restrict__ bi, float* __restrict__ h)
{
  int idx = blockIdx.x*256 + threadIdx.x;
  int b = idx >> 9, d = idx & 511;
  const float* xr = x + b*68 + 4;
  const float* wr = w + d*64;
  float a = bi[d];
#pragma unroll
  for(int f=0; f<64; f++) a += xr[f]*wr[f];
  h[idx] = fmaxf(a, 0.f);
}

__global__ __launch_bounds__(256) void ln_kernel(
  float* __restrict__ h, const float* __restrict__ pz, int nz,
  const float* __restrict__ g, const float* __restrict__ bta,
  u16* __restrict__ hn)
{
  int row = blockIdx.x;
  int t = threadIdx.x;
  float v0 = h[row*512 + t], v1 = h[row*512 + 256 + t];
  for(int z=0; z<nz; z++){
    v0 += pz[(size_t)z*524288 + row*512 + t];
    v1 += pz[(size_t)z*524288 + row*512 + 256 + t];
  }
  if(nz){ h[row*512+t] = v0; h[row*512+256+t] = v1; }
  float s = v0+v1, s2 = v0*v0 + v1*v1;
#pragma unroll
  for(int off=32; off; off>>=1){ s += __shfl_down(s, off); s2 += __shfl_down(s2, off); }
  __shared__ float red[8];
  int wid = t>>6;
  if((t&63)==0){ red[wid*2]=s; red[wid*2+1]=s2; }
  __syncthreads();
  float mu = (red[0]+red[2]+red[4]+red[6]) * (1.f/512.f);
  float ms = (red[1]+red[3]+red[5]+red[7]) * (1.f/512.f);
  float rstd = rsqrtf(ms - mu*mu + 1e-5f);
  hn[row*512+t]     = f2bf((v0-mu)*rstd*g[t]     + bta[t]);
  hn[row*512+256+t] = f2bf((v1-mu)*rstd*g[t+256] + bta[t+256]);
}

__global__ __launch_bounds__(256) void sdt_kernel(
  const float* __restrict__ xp, u16* __restrict__ dtb, float* __restrict__ sb)
{
  int t = threadIdx.x;
  int row = blockIdx.x*32 + (t>>3);
  int sub = t&7;
  const float* xr = xp + row*96;
  float a = 0.f;
#pragma unroll
  for(int i=0;i<4;i++){
    int n = sub + 8*i;
    float Bn=0.f, Cn=0.f;
#pragma unroll
    for(int z=0;z<8;z++){ Bn += xr[(size_t)z*98304 + 32+n]; Cn += xr[(size_t)z*98304 + 64+n]; }
    a += Bn*Cn;
  }
  a += __shfl_xor(a,1); a += __shfl_xor(a,2); a += __shfl_xor(a,4);
  if(sub==0) sb[row] = a;
#pragma unroll
  for(int i=0;i<4;i++){
    int r = sub + 8*i;
    float d=0.f;
#pragma unroll
    for(int z=0;z<8;z++) d += xr[(size_t)z*98304 + r];
    dtb[row*32+r] = f2bf(d);
  }
}

template<int BM,int BN,int WM,int WN,int MODE>
__global__ __launch_bounds__(256)
void gemm_mfma(const u16* __restrict__ A, int lda,
               const u16* __restrict__ B, int ldb, int Klen,
               const float* __restrict__ p0, const float* __restrict__ p1,
               const float* __restrict__ p2,
               const u16* __restrict__ q0, const u16* __restrict__ q1,
               u16* __restrict__ o16a, u16* __restrict__ o16b,
               float* __restrict__ o32)
{
  constexpr int MI = WM/16, NI = WN/16;
  constexpr int WCOLS = BN/WN;
  constexpr int LDSK = 40;
  constexpr int CA = BM*4, CB = BN*4;
  constexpr int IA = (CA+255)/256, IB = (CB+255)/256;
  static_assert((BM/WM)*(BN/WN) == 4, "4 waves");
  __shared__ u16 As[BM*LDSK];
  __shared__ u16 Bs[BN*LDSK];
  const int tid  = threadIdx.x;
  const int lane = tid & 63, wid = tid >> 6;
  const int wm = wid / WCOLS, wn = wid % WCOLS;
  const int m0 = blockIdx.y*BM, n0 = blockIdx.x*BN;
  const int k0 = blockIdx.z*Klen;
  const int qd = lane>>4, lr = lane&15;

  v4f acc[MI][NI];
#pragma unroll
  for(int i=0;i<MI;i++)
#pragma unroll
    for(int j=0;j<NI;j++) acc[i][j] = v4f{0.f,0.f,0.f,0.f};

  v8s ra[IA], rb[IB];
  auto loadAB = [&](int kk){
#pragma unroll
    for(int i=0;i<IA;i++){ int s = tid + i*256;
      if(CA%256==0 || s<CA){ int r=s>>2, kg=s&3;
        ra[i] = *(const v8s*)(A + (size_t)(m0+r)*lda + (k0+kk) + kg*8); } }
#pragma unroll
    for(int i=0;i<IB;i++){ int s = tid + i*256;
      if(CB%256==0 || s<CB){ int r=s>>2, kg=s&3;
        rb[i] = *(const v8s*)(B + (size_t)(n0+r)*ldb + (k0+kk) + kg*8); } }
  };

  loadAB(0);
  for(int kk=0; kk<Klen; kk+=32){
    __syncthreads();
#pragma unroll
    for(int i=0;i<IA;i++){ int s = tid + i*256;
      if(CA%256==0 || s<CA){ int r=s>>2, kg=s&3;
        *(v8s*)(As + r*LDSK + kg*8) = ra[i]; } }
#pragma unroll
    for(int i=0;i<IB;i++){ int s = tid + i*256;
      if(CB%256==0 || s<CB){ int r=s>>2, kg=s&3;
        *(v8s*)(Bs + r*LDSK + kg*8) = rb[i]; } }
    __syncthreads();
    if(kk+32 < Klen) loadAB(kk+32);
    v8s af[MI], bfv[NI];
#pragma unroll
    for(int i=0;i<MI;i++) af[i]  = *(const v8s*)(As + (wm*WM + i*16 + lr)*LDSK + qd*8);
#pragma unroll
    for(int j=0;j<NI;j++) bfv[j] = *(const v8s*)(Bs + (wn*WN + j*16 + lr)*LDSK + qd*8);
#pragma unroll
    for(int i=0;i<MI;i++)
#pragma unroll
      for(int j=0;j<NI;j++)
        acc[i][j] = __builtin_amdgcn_mfma_f32_16x16x32_bf16(af[i], bfv[j], acc[i][j], 0,0,0);
  }

#pragma unroll
  for(int i=0;i<MI;i++)
#pragma unroll
    for(int j=0;j<NI;j++){
      const int gb0 = m0 + wm*WM + i*16 + qd*4;
      const int ge  = n0 + wn*WN + j*16 + lr;
#pragma unroll
      for(int r=0;r<4;r++){
        const int gb = gb0 + r;
        float val = acc[i][j][r];
        if constexpr (MODE==0){
          if(ge < 1536){
            float t = val * p0[ge*4+3] + p1[ge];
            o16a[(size_t)gb*1536 + ge] = f2bf(siluf(t));
          } else {
            o16b[(size_t)gb*1536 + (ge-1536)] = f2bf(siluf(val));
          }
        } else if constexpr (MODE==1){
          o32[(size_t)blockIdx.z*98304 + (size_t)gb*96 + ge] = val;
        } else if constexpr (MODE==2){
          float delta = softplusf(val + p0[ge]);
          float uu = bf2f(q0[(size_t)gb*1536+ge]);
          float zz = bf2f(q1[(size_t)gb*1536+ge]);
          o16a[(size_t)gb*1536+ge] = f2bf(uu*(delta*p2[gb] + p1[ge])*zz);
        } else {
          o32[(size_t)blockIdx.z*524288 + (size_t)gb*512 + ge] = val;
        }
      }
    }
}

__global__ __launch_bounds__(256) void head_kernel(
  const float* __restrict__ x, const float* __restrict__ h,
  const float* __restrict__ pz,
  const float* __restrict__ wlog, const float* __restrict__ blog,
  const float* __restrict__ wg, const float* __restrict__ bg,
  const float* __restrict__ wh1, const float* __restrict__ bh1,
  const float* __restrict__ wh2, const float* __restrict__ bh2,
  float* __restrict__ out)
{
  int b = blockIdx.x, t = threadIdx.x;
  __shared__ float fused[512];
  __shared__ float part[256];
  __shared__ float z1s[32];
  float lgin = x[b*68+0]*wlog[0] + x[b*68+1]*wlog[1]
             + x[b*68+2]*wlog[2] + x[b*68+3]*wlog[3] + blog[0];
  float lg = 1.f/(1.f+__expf(-lgin));
  for(int d=t; d<512; d+=256){
    float m = h[(size_t)b*512+d]
            + pz[(size_t)0*524288 + b*512 + d]
            + pz[(size_t)1*524288 + b*512 + d]
            + pz[(size_t)2*524288 + b*512 + d];
    fused[d] = m*(lg*wg[d] + bg[d]);
  }
  __syncthreads();
  int j = t&31, c = t>>5;
  float p = 0.f;
#pragma unroll
  for(int i=0;i<64;i++){ int d = c*64+i; p += fused[d]*wh1[j*512+d]; }
  part[t] = p;
  __syncthreads();
  if(t < 32){
    float z = bh1[t];
#pragma unroll
    for(int cc=0; cc<8; cc++) z += part[cc*32+t];
    z1s[t] = fmaxf(z, 0.f);
  }
  __syncthreads();
  if(t==0){
    float lo = bh2[0];
#pragma unroll
    for(int jj=0;jj<32;jj++) lo += z1s[jj]*wh2[jj];
    out[b] = 1.f/(1.f+__expf(-lo));
  }
}

// ===========================================================================
extern "C" void kernel_launch(void* const* d_in, const int* in_sizes, int n_in,
                              void* d_out, int out_size, void* d_ws, size_t ws_size,
                              hipStream_t stream)
{
  const float* x        = (const float*)d_in[0];
  const float* w_in     = (const float*)d_in[1];
  const float* b_in     = (const float*)d_in[2];
  const float* ln_g     = (const float*)d_in[3];
  const float* ln_b     = (const float*)d_in[4];
  const float* W_inproj = (const float*)d_in[5];
  const float* conv_w   = (const float*)d_in[6];
  const float* conv_b   = (const float*)d_in[7];
  const float* W_xproj  = (const float*)d_in[8];
  const float* W_dt     = (const float*)d_in[9];
  const float* b_dt     = (const float*)d_in[10];
  // d_in[11] A_log: dead — scan is a single step from h0=0
  const float* D_skip   = (const float*)d_in[12];
  const float* W_outproj= (const float*)d_in[13];
  const float* w_log    = (const float*)d_in[14];
  const float* b_log    = (const float*)d_in[15];
  const float* W_gate   = (const float*)d_in[16];
  const float* b_gate   = (const float*)d_in[17];
  const float* W_h1     = (const float*)d_in[18];
  const float* b_h1     = (const float*)d_in[19];
  const float* W_h2     = (const float*)d_in[20];
  const float* b_h2     = (const float*)d_in[21];
  float* out = (float*)d_out;
  (void)in_sizes; (void)n_in; (void)out_size; (void)ws_size;

  char* ws = (char*)d_ws;
  size_t off = 0;
  auto alloc = [&](size_t bytes)->char*{
    char* p = ws + off; off = (off + bytes + 255) & ~(size_t)255; return p; };
  // fallback-path weight copies (unused by mega path)
  u16*   wInB  = (u16*)  alloc(6291456u*2);
  u16*   wXB   = (u16*)  alloc(589824u*2);
  u16*   wDtB  = (u16*)  alloc(196608u*2);
  u16*   wOutB = (u16*)  alloc(3145728u*2);
  float* h     = (float*)alloc(524288u*4);
  u16*   hn    = (u16*)  alloc(524288u*2);
  u16*   u     = (u16*)  alloc(1572864u*2);
  u16*   zs    = (u16*)  alloc(1572864u*2);
  float* xpart = (float*)alloc(8u*98304u*4);
  u16*   dtb   = (u16*)  alloc(32768u*2);
  float* sb    = (float*)alloc(1024u*4);
  u16*   y     = (u16*)  alloc(1572864u*2);
  float* hpart = (float*)alloc(3u*524288u*4);

  // ---- primary: cooperative mega-kernel ----
  Params prm;
  prm.x=x; prm.w_in=w_in; prm.b_in=b_in; prm.ln_g=ln_g; prm.ln_b=ln_b;
  prm.W_inproj=W_inproj; prm.conv_w=conv_w; prm.conv_b=conv_b;
  prm.W_xproj=W_xproj; prm.W_dt=W_dt; prm.b_dt=b_dt; prm.D_skip=D_skip;
  prm.W_outproj=W_outproj; prm.w_log=w_log; prm.b_log=b_log;
  prm.W_gate=W_gate; prm.b_gate=b_gate; prm.W_h1=W_h1; prm.b_h1=b_h1;
  prm.W_h2=W_h2; prm.b_h2=b_h2; prm.out=out;
  prm.h=h; prm.hn=hn; prm.u=u; prm.zs=zs; prm.dtb=dtb; prm.sb=sb; prm.y=y;

  int maxb = 1;
  if(hipOccupancyMaxActiveBlocksPerMultiprocessor(&maxb, mega_kernel, 256, 0)
     != hipSuccess) maxb = 1;
  int grid = 256 * (maxb >= 2 ? 2 : 1);

  void* kargs[] = { &prm };
  hipError_t rc = hipLaunchCooperativeKernel((void*)mega_kernel,
                    dim3(grid), dim3(256), kargs, 0, stream);
  if(rc == hipSuccess) return;

  // ---- fallback: R2 multi-kernel path ----
  cvt_kernel<<<9984,256,0,stream>>>(W_inproj, W_xproj, W_dt, W_outproj,
                                    wInB, wXB, wDtB, wOutB);
  input_kernel<<<2048,256,0,stream>>>(x, w_in, b_in, h);
  for(int l=0;l<4;l++){
    ln_kernel<<<1024,256,0,stream>>>(h, hpart, l?3:0, ln_g+l*512, ln_b+l*512, hn);
    gemm_mfma<64,64,32,32,0><<<dim3(48,16,1),256,0,stream>>>(
      hn, 512, wInB+(size_t)l*1572864, 512, 512,
      conv_w+l*6144, conv_b+l*1536, nullptr, nullptr, nullptr, u, zs, nullptr);
    gemm_mfma<64,96,32,48,1><<<dim3(1,16,8),256,0,stream>>>(
      u, 1536, wXB+(size_t)l*147456, 1536, 192,
      nullptr, nullptr, nullptr, nullptr, nullptr, nullptr, nullptr, xpart);
    sdt_kernel<<<32,256,0,stream>>>(xpart, dtb, sb);
    gemm_mfma<64,64,32,32,2><<<dim3(24,16,1),256,0,stream>>>(
      dtb, 32, wDtB+(size_t)l*49152, 32, 32,
      b_dt+l*1536, D_skip+l*1536, sb, u, zs, y, nullptr, nullptr);
    gemm_mfma<64,64,32,32,3><<<dim3(8,16,3),256,0,stream>>>(
      y, 1536, wOutB+(size_t)l*786432, 1536, 512,
      nullptr, nullptr, nullptr, nullptr, nullptr, nullptr, nullptr, hpart);
  }
  head_kernel<<<1024,256,0,stream>>>(x, h, hpart, w_log, b_log, W_gate, b_gate,
                                     W_h1, b_h1, W_h2, b_h2, out);
}

// Round 4
// 377.418 us; speedup vs baseline: 2.8942x; 2.8942x over previous
//
#include <hip/hip_runtime.h>

typedef unsigned short u16;
typedef short v8s __attribute__((ext_vector_type(8)));
typedef float v4f __attribute__((ext_vector_type(4)));
typedef u16  v4u __attribute__((ext_vector_type(4)));

__device__ __forceinline__ float bf2f(u16 h){ return __uint_as_float(((unsigned)h)<<16); }
__device__ __forceinline__ u16 f2bf(float f){
  unsigned u = __float_as_uint(f);
  u += 0x7FFFu + ((u>>16)&1u);
  return (u16)(u>>16);
}
__device__ __forceinline__ float siluf(float x){ return x/(1.f+__expf(-x)); }
__device__ __forceinline__ float softplusf(float x){
  return (x>15.f) ? x : __logf(1.f+__expf(x));
}

// ---------------------------------------------------------------------------
// Input MLP: h[b,d] = relu(sum_f x[b,4+f]*w_in[d,f] + b_in[d])   (1024x512 f32)
// ---------------------------------------------------------------------------
__global__ __launch_bounds__(256) void input_kernel(
  const float* __restrict__ x, const float* __restrict__ w,
  const float* __restrict__ bi, float* __restrict__ h)
{
  int idx = blockIdx.x*256 + threadIdx.x;
  int b = idx >> 9, d = idx & 511;
  const float* xr = x + b*68 + 4;
  const float* wr = w + d*64;
  float a = bi[d];
#pragma unroll
  for(int f=0; f<64; f++) a += xr[f]*wr[f];
  h[idx] = fmaxf(a, 0.f);
}

// ---------------------------------------------------------------------------
// GEMM1 with fused LayerNorm: per block, compute mu/rstd for its 64 rows of
// the f32 residual h, then K-loop stages A = LN(h)->bf16 and B = W_inproj
// f32->bf16, depth-2 register prefetch. Epilogue: u=silu(conv tap), zs=silu(z).
// grid (48 nt, 16 mt). N=3072, K=512.
// ---------------------------------------------------------------------------
__global__ __launch_bounds__(256) void gemm1_ln(
  const float* __restrict__ h, const float* __restrict__ g,
  const float* __restrict__ bta, const float* __restrict__ Wip,
  const float* __restrict__ convw, const float* __restrict__ convb,
  u16* __restrict__ u, u16* __restrict__ zs)
{
  __shared__ u16 As[64*40];
  __shared__ u16 Bs[64*40];
  __shared__ float mu_s[64], rs_s[64];
  __shared__ float gs[512], bs2[512];
  const int tid=threadIdx.x, lane=tid&63, wid=tid>>6;
  const int wm=wid>>1, wn=wid&1;
  const int qd=lane>>4, lr=lane&15;
  const int m0=blockIdx.y*64, n0=blockIdx.x*64;

  // stage ln gamma/beta to LDS
  if(tid<128)      ((float4*)gs)[tid]      = ((const float4*)g)[tid];
  else             ((float4*)bs2)[tid-128] = ((const float4*)bta)[tid-128];

  // stats: 4 threads per row
  {
    int r=tid>>2, q=tid&3;
    const float4* hr = (const float4*)(h + (size_t)(m0+r)*512 + q*128);
    float s=0.f, s2=0.f;
#pragma unroll
    for(int i=0;i<32;i++){
      float4 v=hr[i];
      s += v.x+v.y+v.z+v.w;
      s2 += v.x*v.x+v.y*v.y+v.z*v.z+v.w*v.w;
    }
    s  += __shfl_xor(s,1);  s  += __shfl_xor(s,2);
    s2 += __shfl_xor(s2,1); s2 += __shfl_xor(s2,2);
    if(q==0){
      float mu = s*(1.f/512.f);
      mu_s[r]=mu;
      rs_s[r]=rsqrtf(s2*(1.f/512.f) - mu*mu + 1e-5f);
    }
  }
  __syncthreads();

  v4f acc[2][2];
#pragma unroll
  for(int i=0;i<2;i++)
#pragma unroll
    for(int j=0;j<2;j++) acc[i][j]=v4f{0.f,0.f,0.f,0.f};

  float4 raf[2][2], rbf[2][2];
  auto loadA=[&](int set,int kk){
#pragma unroll
    for(int i=0;i<2;i++){ int s=tid+i*256; int r=s>>3, kc=s&7;
      raf[set][i]=*(const float4*)(h+(size_t)(m0+r)*512+kk+kc*4); }
  };
  auto loadB=[&](int set,int kk){
#pragma unroll
    for(int i=0;i<2;i++){ int s=tid+i*256; int r=s>>3, kc=s&7;
      rbf[set][i]=*(const float4*)(Wip+(size_t)(n0+r)*512+kk+kc*4); }
  };
  loadA(0,0); loadB(0,0); loadA(1,32); loadB(1,32);

  for(int it=0; it<16; it++){
    const int kk=it*32, set=it&1;
    __syncthreads();
#pragma unroll
    for(int i=0;i<2;i++){ int s=tid+i*256; int r=s>>3, kc=s&7;
      float4 v=raf[set][i];
      float mu=mu_s[r], rs=rs_s[r];
      int c = kk+kc*4;
      v4u pk = { f2bf((v.x-mu)*rs*gs[c  ]+bs2[c  ]),
                 f2bf((v.y-mu)*rs*gs[c+1]+bs2[c+1]),
                 f2bf((v.z-mu)*rs*gs[c+2]+bs2[c+2]),
                 f2bf((v.w-mu)*rs*gs[c+3]+bs2[c+3]) };
      *(v4u*)(As+r*40+kc*4)=pk;
    }
#pragma unroll
    for(int i=0;i<2;i++){ int s=tid+i*256; int r=s>>3, kc=s&7;
      float4 v=rbf[set][i];
      v4u pk={ f2bf(v.x), f2bf(v.y), f2bf(v.z), f2bf(v.w) };
      *(v4u*)(Bs+r*40+kc*4)=pk;
    }
    __syncthreads();
    if(it+2<16){ loadA(set,kk+64); loadB(set,kk+64); }
    v8s af[2], bfv[2];
#pragma unroll
    for(int i=0;i<2;i++) af[i] =*(const v8s*)(As+(wm*32+i*16+lr)*40+qd*8);
#pragma unroll
    for(int j=0;j<2;j++) bfv[j]=*(const v8s*)(Bs+(wn*32+j*16+lr)*40+qd*8);
#pragma unroll
    for(int i=0;i<2;i++)
#pragma unroll
      for(int j=0;j<2;j++)
        acc[i][j]=__builtin_amdgcn_mfma_f32_16x16x32_bf16(af[i],bfv[j],acc[i][j],0,0,0);
  }

#pragma unroll
  for(int i=0;i<2;i++)
#pragma unroll
    for(int j=0;j<2;j++){
      const int gb0=m0+wm*32+i*16+qd*4;
      const int ge =n0+wn*32+j*16+lr;
#pragma unroll
      for(int r=0;r<4;r++){
        const int gb=gb0+r;
        float val=acc[i][j][r];
        if(ge<1536){
          float t=val*convw[ge*4+3]+convb[ge];
          u[(size_t)gb*1536+ge]=f2bf(siluf(t));
        }else{
          zs[(size_t)gb*1536+(ge-1536)]=f2bf(siluf(val));
        }
      }
    }
}

// ---------------------------------------------------------------------------
// GEMM2: u(1024x1536,bf16) @ W_xproj^T(96x1536,f32) split-K=8 -> xpart slices.
// grid (1, 16 mt, 8 z). BM=64 BN=96 WM=32 WN=48, Klen=192 (6 iters).
// ---------------------------------------------------------------------------
__global__ __launch_bounds__(256) void gemm2_k(
  const u16* __restrict__ A, const float* __restrict__ Bw,
  float* __restrict__ xpart)
{
  __shared__ u16 As[64*40];
  __shared__ u16 Bs[96*40];
  const int tid=threadIdx.x, lane=tid&63, wid=tid>>6;
  const int wm=wid>>1, wn=wid&1;
  const int qd=lane>>4, lr=lane&15;
  const int m0=blockIdx.y*64;
  const int k0=blockIdx.z*192;

  v4f acc[2][3];
#pragma unroll
  for(int i=0;i<2;i++)
#pragma unroll
    for(int j=0;j<3;j++) acc[i][j]=v4f{0.f,0.f,0.f,0.f};

  v8s ra[2][1]; float4 rb[2][3];
  auto loadA=[&](int set,int kk){
    int r=tid>>2, kg=tid&3;
    ra[set][0]=*(const v8s*)(A+(size_t)(m0+r)*1536+kk+kg*8);
  };
  auto loadB=[&](int set,int kk){
#pragma unroll
    for(int i=0;i<3;i++){ int s=tid+i*256; int r=s>>3, kc=s&7;
      rb[set][i]=*(const float4*)(Bw+(size_t)r*1536+kk+kc*4); }
  };
  loadA(0,k0); loadB(0,k0); loadA(1,k0+32); loadB(1,k0+32);

  for(int it=0; it<6; it++){
    const int kk=k0+it*32, set=it&1;
    __syncthreads();
    { int r=tid>>2, kg=tid&3; *(v8s*)(As+r*40+kg*8)=ra[set][0]; }
#pragma unroll
    for(int i=0;i<3;i++){ int s=tid+i*256; int r=s>>3, kc=s&7;
      float4 v=rb[set][i];
      v4u pk={ f2bf(v.x), f2bf(v.y), f2bf(v.z), f2bf(v.w) };
      *(v4u*)(Bs+r*40+kc*4)=pk;
    }
    __syncthreads();
    if(it+2<6){ loadA(set,kk+64); loadB(set,kk+64); }
    v8s af[2], bfv[3];
#pragma unroll
    for(int i=0;i<2;i++) af[i] =*(const v8s*)(As+(wm*32+i*16+lr)*40+qd*8);
#pragma unroll
    for(int j=0;j<3;j++) bfv[j]=*(const v8s*)(Bs+(wn*48+j*16+lr)*40+qd*8);
#pragma unroll
    for(int i=0;i<2;i++)
#pragma unroll
      for(int j=0;j<3;j++)
        acc[i][j]=__builtin_amdgcn_mfma_f32_16x16x32_bf16(af[i],bfv[j],acc[i][j],0,0,0);
  }

#pragma unroll
  for(int i=0;i<2;i++)
#pragma unroll
    for(int j=0;j<3;j++){
      const int gb0=m0+wm*32+i*16+qd*4;
      const int ge =wn*48+j*16+lr;
#pragma unroll
      for(int r=0;r<4;r++)
        xpart[(size_t)blockIdx.z*98304+(size_t)(gb0+r)*96+ge]=acc[i][j][r];
    }
}

// ---------------------------------------------------------------------------
// Sum GEMM2's 8 split-K partials -> s[b]=dot(Bm,Cm), dt as bf16.
// ---------------------------------------------------------------------------
__global__ __launch_bounds__(256) void sdt_kernel(
  const float* __restrict__ xp, u16* __restrict__ dtb, float* __restrict__ sb)
{
  int t = threadIdx.x;
  int row = blockIdx.x*32 + (t>>3);
  int sub = t&7;
  const float* xr = xp + row*96;
  float a = 0.f;
#pragma unroll
  for(int i=0;i<4;i++){
    int n = sub + 8*i;
    float Bn=0.f, Cn=0.f;
#pragma unroll
    for(int z=0;z<8;z++){ Bn += xr[(size_t)z*98304 + 32+n]; Cn += xr[(size_t)z*98304 + 64+n]; }
    a += Bn*Cn;
  }
  a += __shfl_xor(a,1); a += __shfl_xor(a,2); a += __shfl_xor(a,4);
  if(sub==0) sb[row] = a;
#pragma unroll
  for(int i=0;i<4;i++){
    int r = sub + 8*i;
    float d=0.f;
#pragma unroll
    for(int z=0;z<8;z++) d += xr[(size_t)z*98304 + r];
    dtb[row*32+r] = f2bf(d);
  }
}

// ---------------------------------------------------------------------------
// GEMM3: dtb(1024x32,bf16) @ W_dt^T(1536x32,f32). K=32 one-shot.
// Epilogue: y = u*(softplus(acc+bdt)*s + Dp)*zs  (bf16). grid (24 nt, 16 mt).
// ---------------------------------------------------------------------------
__global__ __launch_bounds__(256) void gemm3_k(
  const u16* __restrict__ A, const float* __restrict__ Bw,
  const float* __restrict__ bdt, const float* __restrict__ Dp,
  const float* __restrict__ sb,
  const u16* __restrict__ u, const u16* __restrict__ zs,
  u16* __restrict__ y)
{
  __shared__ u16 As[64*40];
  __shared__ u16 Bs[64*40];
  const int tid=threadIdx.x, lane=tid&63, wid=tid>>6;
  const int wm=wid>>1, wn=wid&1;
  const int qd=lane>>4, lr=lane&15;
  const int m0=blockIdx.y*64, n0=blockIdx.x*64;

  { int r=tid>>2, kg=tid&3;
    *(v8s*)(As+r*40+kg*8)=*(const v8s*)(A+(size_t)(m0+r)*32+kg*8); }
#pragma unroll
  for(int i=0;i<2;i++){ int s=tid+i*256; int r=s>>3, kc=s&7;
    float4 v=*(const float4*)(Bw+(size_t)(n0+r)*32+kc*4);
    v4u pk={ f2bf(v.x), f2bf(v.y), f2bf(v.z), f2bf(v.w) };
    *(v4u*)(Bs+r*40+kc*4)=pk;
  }
  __syncthreads();

  v4f acc[2][2];
#pragma unroll
  for(int i=0;i<2;i++)
#pragma unroll
    for(int j=0;j<2;j++) acc[i][j]=v4f{0.f,0.f,0.f,0.f};
  v8s af[2], bfv[2];
#pragma unroll
  for(int i=0;i<2;i++) af[i] =*(const v8s*)(As+(wm*32+i*16+lr)*40+qd*8);
#pragma unroll
  for(int j=0;j<2;j++) bfv[j]=*(const v8s*)(Bs+(wn*32+j*16+lr)*40+qd*8);
#pragma unroll
  for(int i=0;i<2;i++)
#pragma unroll
    for(int j=0;j<2;j++)
      acc[i][j]=__builtin_amdgcn_mfma_f32_16x16x32_bf16(af[i],bfv[j],acc[i][j],0,0,0);

#pragma unroll
  for(int i=0;i<2;i++)
#pragma unroll
    for(int j=0;j<2;j++){
      const int gb0=m0+wm*32+i*16+qd*4;
      const int ge =n0+wn*32+j*16+lr;
#pragma unroll
      for(int r=0;r<4;r++){
        const int gb=gb0+r;
        float delta=softplusf(acc[i][j][r]+bdt[ge]);
        float uu=bf2f(u[(size_t)gb*1536+ge]);
        float zz=bf2f(zs[(size_t)gb*1536+ge]);
        y[(size_t)gb*1536+ge]=f2bf(uu*(delta*sb[gb]+Dp[ge])*zz);
      }
    }
}

// ---------------------------------------------------------------------------
// GEMM4: y(1024x1536,bf16) @ W_outproj^T(512x1536,f32), split-K=3,
// atomicAdd into f32 residual h. grid (8 nt, 16 mt, 3 z). Klen=512 (16 iters).
// ---------------------------------------------------------------------------
__global__ __launch_bounds__(256) void gemm4_k(
  const u16* __restrict__ A, const float* __restrict__ Bw,
  float* __restrict__ h)
{
  __shared__ u16 As[64*40];
  __shared__ u16 Bs[64*40];
  const int tid=threadIdx.x, lane=tid&63, wid=tid>>6;
  const int wm=wid>>1, wn=wid&1;
  const int qd=lane>>4, lr=lane&15;
  const int m0=blockIdx.y*64, n0=blockIdx.x*64;
  const int k0=blockIdx.z*512;

  v4f acc[2][2];
#pragma unroll
  for(int i=0;i<2;i++)
#pragma unroll
    for(int j=0;j<2;j++) acc[i][j]=v4f{0.f,0.f,0.f,0.f};

  v8s ra[2][1]; float4 rb[2][2];
  auto loadA=[&](int set,int kk){
    int r=tid>>2, kg=tid&3;
    ra[set][0]=*(const v8s*)(A+(size_t)(m0+r)*1536+kk+kg*8);
  };
  auto loadB=[&](int set,int kk){
#pragma unroll
    for(int i=0;i<2;i++){ int s=tid+i*256; int r=s>>3, kc=s&7;
      rb[set][i]=*(const float4*)(Bw+(size_t)(n0+r)*1536+kk+kc*4); }
  };
  loadA(0,k0); loadB(0,k0); loadA(1,k0+32); loadB(1,k0+32);

  for(int it=0; it<16; it++){
    const int kk=k0+it*32, set=it&1;
    __syncthreads();
    { int r=tid>>2, kg=tid&3; *(v8s*)(As+r*40+kg*8)=ra[set][0]; }
#pragma unroll
    for(int i=0;i<2;i++){ int s=tid+i*256; int r=s>>3, kc=s&7;
      float4 v=rb[set][i];
      v4u pk={ f2bf(v.x), f2bf(v.y), f2bf(v.z), f2bf(v.w) };
      *(v4u*)(Bs+r*40+kc*4)=pk;
    }
    __syncthreads();
    if(it+2<16){ loadA(set,kk+64); loadB(set,kk+64); }
    v8s af[2], bfv[2];
#pragma unroll
    for(int i=0;i<2;i++) af[i] =*(const v8s*)(As+(wm*32+i*16+lr)*40+qd*8);
#pragma unroll
    for(int j=0;j<2;j++) bfv[j]=*(const v8s*)(Bs+(wn*32+j*16+lr)*40+qd*8);
#pragma unroll
    for(int i=0;i<2;i++)
#pragma unroll
      for(int j=0;j<2;j++)
        acc[i][j]=__builtin_amdgcn_mfma_f32_16x16x32_bf16(af[i],bfv[j],acc[i][j],0,0,0);
  }

#pragma unroll
  for(int i=0;i<2;i++)
#pragma unroll
    for(int j=0;j<2;j++){
      const int gb0=m0+wm*32+i*16+qd*4;
      const int ge =n0+wn*32+j*16+lr;
#pragma unroll
      for(int r=0;r<4;r++)
        atomicAdd(h+(size_t)(gb0+r)*512+ge, acc[i][j][r]);
    }
}

// ---------------------------------------------------------------------------
// Head: lg/gate/MLP/sigmoid from final residual h. One block per row.
// ---------------------------------------------------------------------------
__global__ __launch_bounds__(256) void head_kernel(
  const float* __restrict__ x, const float* __restrict__ h,
  const float* __restrict__ wlog, const float* __restrict__ blog,
  const float* __restrict__ wg, const float* __restrict__ bg,
  const float* __restrict__ wh1, const float* __restrict__ bh1,
  const float* __restrict__ wh2, const float* __restrict__ bh2,
  float* __restrict__ out)
{
  int b = blockIdx.x, t = threadIdx.x;
  __shared__ float fused[512];
  __shared__ float part[256];
  __shared__ float z1s[32];
  float lgin = x[b*68+0]*wlog[0] + x[b*68+1]*wlog[1]
             + x[b*68+2]*wlog[2] + x[b*68+3]*wlog[3] + blog[0];
  float lg = 1.f/(1.f+__expf(-lgin));
  for(int d=t; d<512; d+=256)
    fused[d] = h[(size_t)b*512+d]*(lg*wg[d] + bg[d]);
  __syncthreads();
  int j = t&31, c = t>>5;
  float p = 0.f;
#pragma unroll
  for(int i=0;i<64;i++){ int d = c*64+i; p += fused[d]*wh1[j*512+d]; }
  part[t] = p;
  __syncthreads();
  if(t < 32){
    float z = bh1[t];
#pragma unroll
    for(int cc=0; cc<8; cc++) z += part[cc*32+t];
    z1s[t] = fmaxf(z, 0.f);
  }
  __syncthreads();
  if(t==0){
    float lo = bh2[0];
#pragma unroll
    for(int jj=0;jj<32;jj++) lo += z1s[jj]*wh2[jj];
    out[b] = 1.f/(1.f+__expf(-lo));
  }
}

// ---------------------------------------------------------------------------
extern "C" void kernel_launch(void* const* d_in, const int* in_sizes, int n_in,
                              void* d_out, int out_size, void* d_ws, size_t ws_size,
                              hipStream_t stream)
{
  const float* x        = (const float*)d_in[0];
  const float* w_in     = (const float*)d_in[1];
  const float* b_in     = (const float*)d_in[2];
  const float* ln_g     = (const float*)d_in[3];
  const float* ln_b     = (const float*)d_in[4];
  const float* W_inproj = (const float*)d_in[5];
  const float* conv_w   = (const float*)d_in[6];
  const float* conv_b   = (const float*)d_in[7];
  const float* W_xproj  = (const float*)d_in[8];
  const float* W_dt     = (const float*)d_in[9];
  const float* b_dt     = (const float*)d_in[10];
  // d_in[11] A_log: dead — scan is a single step from h0=0
  const float* D_skip   = (const float*)d_in[12];
  const float* W_outproj= (const float*)d_in[13];
  const float* w_log    = (const float*)d_in[14];
  const float* b_log    = (const float*)d_in[15];
  const float* W_gate   = (const float*)d_in[16];
  const float* b_gate   = (const float*)d_in[17];
  const float* W_h1     = (const float*)d_in[18];
  const float* b_h1     = (const float*)d_in[19];
  const float* W_h2     = (const float*)d_in[20];
  const float* b_h2     = (const float*)d_in[21];
  float* out = (float*)d_out;
  (void)in_sizes; (void)n_in; (void)out_size; (void)ws_size;

  char* ws = (char*)d_ws;
  size_t off = 0;
  auto alloc = [&](size_t bytes)->char*{
    char* p = ws + off; off = (off + bytes + 255) & ~(size_t)255; return p; };
  float* h     = (float*)alloc(524288u*4);    // 1024x512 f32 residual
  u16*   u     = (u16*)  alloc(1572864u*2);   // 1024x1536
  u16*   zs    = (u16*)  alloc(1572864u*2);   // silu(z)
  float* xpart = (float*)alloc(8u*98304u*4);  // GEMM2 split-K partials
  u16*   dtb   = (u16*)  alloc(32768u*2);     // 1024x32
  float* sb    = (float*)alloc(1024u*4);      // s[b]
  u16*   y     = (u16*)  alloc(1572864u*2);   // 1024x1536

  input_kernel<<<2048,256,0,stream>>>(x, w_in, b_in, h);

  for(int l=0;l<4;l++){
    gemm1_ln<<<dim3(48,16),256,0,stream>>>(
      h, ln_g+l*512, ln_b+l*512, W_inproj+(size_t)l*1572864,
      conv_w+l*6144, conv_b+l*1536, u, zs);
    gemm2_k<<<dim3(1,16,8),256,0,stream>>>(
      u, W_xproj+(size_t)l*147456, xpart);
    sdt_kernel<<<32,256,0,stream>>>(xpart, dtb, sb);
    gemm3_k<<<dim3(24,16),256,0,stream>>>(
      dtb, W_dt+(size_t)l*49152, b_dt+l*1536, D_skip+l*1536, sb, u, zs, y);
    gemm4_k<<<dim3(8,16,3),256,0,stream>>>(
      y, W_outproj+(size_t)l*786432, h);
  }

  head_kernel<<<1024,256,0,stream>>>(x, h, w_log, b_log, W_gate, b_gate,
                                     W_h1, b_h1, W_h2, b_h2, out);
}